// Round 1
// baseline (421.623 us; speedup 1.0000x reference)
//
#include <hip/hip_runtime.h>
#include <stdint.h>
#include <stddef.h>

// Problem constants (fixed by the reference).
constexpr int N_NODES = 10000;
constexpr int N_EDGES = 320000;
constexpr int DIM_IN  = 128;
constexpr int DIM_H   = 256;
constexpr int DIM_C   = 32;
constexpr int DIM_OUT = 64;
constexpr int DIM_QKV = DIM_C + DIM_C + DIM_H;  // 320 : [q|k|v]
constexpr int DIM_QK  = 2 * DIM_C;              // 64  : [q|k] compact fp32
constexpr int DIM_CAT = 2 * DIM_H;              // 512 : [h|comm]
constexpr float SCALE = 0.17677669529663687f;   // 1/sqrt(32)
constexpr int MAXD = 192;   // bucket capacity; Binomial(320k,1e-4) max ~66 (28 sigma margin)
constexpr float VSCALE = 64.0f;                 // fp8 v pre-scale (|v|max ~0.5 -> ~32 << 448)

constexpr int NBLK = 256;   // persistent grid: <= 1 CU of resources per block -> always co-resident
constexpr int NTHR = 256;
constexpr int PAD  = 40;    // LDS row stride in bf16 (+8 pad: 2-way banks max, free)

#if __has_builtin(__builtin_amdgcn_cvt_pk_f32_fp8) && __has_builtin(__builtin_amdgcn_cvt_pk_fp8_f32)
#define V_FP8 1
#else
#define V_FP8 0   // fallback: bf16 v
#endif

// ---------------- workspace layout (4-byte words) ----------------
constexpr size_t alignw(size_t w) { return (w + 15) & ~size_t(15); }
constexpr size_t OFF_DEG   = 0;
constexpr size_t OFF_BAR   = OFF_DEG + N_NODES;                          // 16 ints: grid barriers
constexpr size_t OFF_COL   = alignw(OFF_BAR + 16);                       // [N][MAXD] bucket
constexpr size_t OFF_QK    = alignw(OFF_COL + (size_t)N_NODES * MAXD);   // fp32 [N][64]
constexpr size_t OFF_BQKV  = alignw(OFF_QK + (size_t)N_NODES * DIM_QK);
constexpr size_t OFF_VT    = alignw(OFF_BQKV + DIM_QKV);                        // [N][256] fp8/bf16
constexpr size_t OFF_XBF   = alignw(OFF_VT + (size_t)N_NODES * DIM_H / 2);      // [N][128]
constexpr size_t OFF_CATBF = alignw(OFF_XBF + (size_t)N_NODES * DIM_IN / 2);    // [N][512]
constexpr size_t OFF_WINT  = alignw(OFF_CATBF + (size_t)N_NODES * DIM_CAT / 2); // [256][128]
constexpr size_t OFF_WQKVT = alignw(OFF_WINT + (size_t)DIM_H * DIM_IN / 2);     // [320][256]
constexpr size_t OFF_W1T   = alignw(OFF_WQKVT + (size_t)DIM_QKV * DIM_H / 2);   // [256][512]
constexpr size_t OFF_W2T   = alignw(OFF_W1T + (size_t)DIM_H * DIM_CAT / 2);     // [64][256]

typedef __attribute__((ext_vector_type(8))) short short8;
typedef __attribute__((ext_vector_type(4))) float floatx4;
typedef __attribute__((ext_vector_type(2))) float floatx2;

#define MFMA16 __builtin_amdgcn_mfma_f32_16x16x32_bf16

__device__ inline unsigned short f2bf(float f) {
    uint32_t u = __builtin_bit_cast(uint32_t, f);
    uint32_t r = (u + 0x7fffu + ((u >> 16) & 1u)) >> 16;   // RNE
    return (unsigned short)r;
}
__device__ inline float bf2f_lo(uint32_t u) { return __builtin_bit_cast(float, u << 16); }
__device__ inline float bf2f_hi(uint32_t u) { return __builtin_bit_cast(float, u & 0xffff0000u); }

// Device-scope spin barrier. Safe: 256 blocks, each needs <= 1 CU of resources on a
// 256-CU chip -> all blocks schedulable immediately regardless of placement skew.
// Release on arrive / acquire on observe (compiler emits L2 wb / L1+L2 inv per the
// gfx950 memory model); __threadfence belt-and-suspenders.
__device__ inline void gbar(int* bar, int idx) {
    __syncthreads();
    if (threadIdx.x == 0) {
        __threadfence();
        __hip_atomic_fetch_add(&bar[idx], 1, __ATOMIC_RELEASE, __HIP_MEMORY_SCOPE_AGENT);
        while (__hip_atomic_load(&bar[idx], __ATOMIC_ACQUIRE, __HIP_MEMORY_SCOPE_AGENT) < NBLK)
            __builtin_amdgcn_s_sleep(2);
        __threadfence();
    }
    __syncthreads();
}

// =====================================================================================
// One persistent kernel; phases separated by grid barriers.
//   P1 prep -> P2 h=x@Win -> P3 qkv=h@Wqkv -> P4 sparse attention -> P5 relu(cat@W1)@W2
// LDS: single 38.4 KB arena, re-carved per phase (max: P5).
// =====================================================================================
__global__ __launch_bounds__(NTHR)
void mega(const float* __restrict__ x, const int* __restrict__ ei,
          const float* __restrict__ W_in, const float* __restrict__ b_in,
          const float* __restrict__ Wq, const float* __restrict__ bq,
          const float* __restrict__ Wk, const float* __restrict__ bk,
          const float* __restrict__ Wv, const float* __restrict__ bv,
          const float* __restrict__ W1, const float* __restrict__ b1,
          const float* __restrict__ W2, const float* __restrict__ b2,
          float* __restrict__ out,
          int* __restrict__ deg, int* __restrict__ bar, int* __restrict__ col,
          float* __restrict__ qk, float* __restrict__ bqkv,
          unsigned short* __restrict__ v_tab, unsigned short* __restrict__ x_bf,
          unsigned short* __restrict__ cat_bf,
          unsigned short* __restrict__ WinT, unsigned short* __restrict__ WqkvT,
          unsigned short* __restrict__ W1T, unsigned short* __restrict__ W2T)
{
    __shared__ alignas(16) char SMEM[38400];
    const int tid   = threadIdx.x;
    const int bid   = blockIdx.x;
    const int wave  = tid >> 6;
    const int lane  = tid & 63;
    const int quad  = lane >> 4;
    const int col16 = lane & 15;
    const int sr    = tid >> 2;          // staging row 0..63
    const int sc    = (tid & 3) * 8;     // staging k-chunk (8 bf16 = 16B)

    // ---------------- P1: prep (edge bucket-scatter, casts, transposes, bias concat) ----
    {
        const int i0 = bid * NTHR + tid;
        const int stride = NBLK * NTHR;   // 65536
        for (int e = i0; e < N_EDGES; e += stride) {
            int src = ei[e];
            int dst = ei[N_EDGES + e];
            int slot = atomicAdd(&deg[src], 1);
            if (slot < MAXD) col[src * MAXD + slot] = dst;
        }
        for (int idx = i0; idx < (N_NODES * DIM_IN) / 8; idx += stride) {
            float4 a = ((const float4*)x)[2 * idx];
            float4 b = ((const float4*)x)[2 * idx + 1];
            uint4 o;
            o.x = (uint32_t)f2bf(a.x) | ((uint32_t)f2bf(a.y) << 16);
            o.y = (uint32_t)f2bf(a.z) | ((uint32_t)f2bf(a.w) << 16);
            o.z = (uint32_t)f2bf(b.x) | ((uint32_t)f2bf(b.y) << 16);
            o.w = (uint32_t)f2bf(b.z) | ((uint32_t)f2bf(b.w) << 16);
            ((uint4*)x_bf)[idx] = o;
        }
        for (int idx = i0; idx < DIM_H * DIM_IN; idx += stride) {        // WinT [256][128]
            int n = idx / DIM_IN, k = idx % DIM_IN;
            WinT[idx] = f2bf(W_in[k * DIM_H + n]);
        }
        for (int idx = i0; idx < DIM_QKV * DIM_H; idx += stride) {       // WqkvT [320][256]
            int n = idx / DIM_H, k = idx % DIM_H;
            float v = (n < DIM_C)     ? Wq[k * DIM_C + n]
                    : (n < 2 * DIM_C) ? Wk[k * DIM_C + (n - DIM_C)]
                                      : Wv[k * DIM_H + (n - 2 * DIM_C)];
            WqkvT[idx] = f2bf(v);
        }
        for (int idx = i0; idx < DIM_H * DIM_CAT; idx += stride) {       // W1T [256][512]
            int n = idx / DIM_CAT, k = idx % DIM_CAT;
            W1T[idx] = f2bf(W1[k * DIM_H + n]);
        }
        for (int idx = i0; idx < DIM_OUT * DIM_H; idx += stride) {       // W2T [64][256]
            int n = idx / DIM_H, k = idx % DIM_H;
            W2T[idx] = f2bf(W2[k * DIM_OUT + n]);
        }
        for (int idx = i0; idx < DIM_QKV; idx += stride)
            bqkv[idx] = (idx < DIM_C) ? bq[idx]
                      : (idx < 2 * DIM_C) ? bk[idx - DIM_C] : bv[idx - 2 * DIM_C];
    }
    gbar(bar, 0);

    // ---------------- P2: h = x @ WinT^T + b_in -> bf16 cat[:, 0:256] ----------------
    // BM=128 BN=128, 4 waves each 64x64 (acc 4x4, 8 ds_reads / 16 MFMA). 158 jobs.
    {
        short* As = (short*)SMEM;              // 128 x PAD
        short* Bs = (short*)(SMEM + 10240);    // 128 x PAD
        if (bid < 2 * ((N_NODES + 127) / 128)) {   // 158
            const int row0 = (bid >> 1) * 128;
            const int col0 = (bid & 1) * 128;
            const int wr = wave >> 1, wc = wave & 1;
            floatx4 acc[4][4] = {};
            for (int k0 = 0; k0 < DIM_IN; k0 += 32) {
                #pragma unroll
                for (int i2 = 0; i2 < 2; ++i2) {
                    int r = sr + i2 * 64, gr = row0 + r;
                    short8 v = {};
                    if (gr < N_NODES) v = *(const short8*)(x_bf + (size_t)gr * DIM_IN + k0 + sc);
                    *(short8*)(As + r * PAD + sc) = v;
                }
                #pragma unroll
                for (int i2 = 0; i2 < 2; ++i2) {
                    int r = sr + i2 * 64;
                    *(short8*)(Bs + r * PAD + sc) =
                        *(const short8*)(WinT + (size_t)(col0 + r) * DIM_IN + k0 + sc);
                }
                __syncthreads();
                short8 af[4], bf[4];
                #pragma unroll
                for (int m = 0; m < 4; ++m)
                    af[m] = *(const short8*)(As + (wr * 64 + m * 16 + col16) * PAD + quad * 8);
                #pragma unroll
                for (int n = 0; n < 4; ++n)
                    bf[n] = *(const short8*)(Bs + (wc * 64 + n * 16 + col16) * PAD + quad * 8);
                #pragma unroll
                for (int m = 0; m < 4; ++m)
                    #pragma unroll
                    for (int n = 0; n < 4; ++n)
                        acc[m][n] = MFMA16(af[m], bf[n], acc[m][n], 0, 0, 0);
                __syncthreads();
            }
            #pragma unroll
            for (int m = 0; m < 4; ++m)
                #pragma unroll
                for (int n = 0; n < 4; ++n) {
                    int gc = col0 + wc * 64 + n * 16 + col16;
                    float bia = b_in[gc];
                    #pragma unroll
                    for (int r = 0; r < 4; ++r) {
                        int gr = row0 + wr * 64 + m * 16 + quad * 4 + r;
                        if (gr < N_NODES)
                            cat_bf[(size_t)gr * DIM_CAT + gc] = f2bf(acc[m][n][r] + bia);
                    }
                }
        }
    }
    gbar(bar, 1);

    // ---------------- P3: qkv = h @ WqkvT^T + bqkv -> qk fp32 [N][64], v fp8 [N][256] --
    // BM=128 BN=160, 4 waves each 64x80 (acc 4x5, 9 ds_reads / 20 MFMA). 158 jobs.
    {
        short* As = (short*)SMEM;              // 128 x PAD
        short* Bs = (short*)(SMEM + 10240);    // 160 x PAD
        if (bid < 2 * ((N_NODES + 127) / 128)) {   // 158
            const int row0 = (bid >> 1) * 128;
            const int col0 = (bid & 1) * 160;
            const int wr = wave >> 1, wc = wave & 1;
            floatx4 acc[4][5] = {};
            for (int k0 = 0; k0 < DIM_H; k0 += 32) {
                #pragma unroll
                for (int i2 = 0; i2 < 2; ++i2) {
                    int r = sr + i2 * 64, gr = row0 + r;
                    short8 v = {};
                    if (gr < N_NODES) v = *(const short8*)(cat_bf + (size_t)gr * DIM_CAT + k0 + sc);
                    *(short8*)(As + r * PAD + sc) = v;
                }
                #pragma unroll
                for (int i2 = 0; i2 < 3; ++i2) {
                    int r = sr + i2 * 64;
                    if (r < 160)
                        *(short8*)(Bs + r * PAD + sc) =
                            *(const short8*)(WqkvT + (size_t)(col0 + r) * DIM_H + k0 + sc);
                }
                __syncthreads();
                short8 af[4], bf[5];
                #pragma unroll
                for (int m = 0; m < 4; ++m)
                    af[m] = *(const short8*)(As + (wr * 64 + m * 16 + col16) * PAD + quad * 8);
                #pragma unroll
                for (int n = 0; n < 5; ++n)
                    bf[n] = *(const short8*)(Bs + (wc * 80 + n * 16 + col16) * PAD + quad * 8);
                #pragma unroll
                for (int m = 0; m < 4; ++m)
                    #pragma unroll
                    for (int n = 0; n < 5; ++n)
                        acc[m][n] = MFMA16(af[m], bf[n], acc[m][n], 0, 0, 0);
                __syncthreads();
            }
            #pragma unroll
            for (int m = 0; m < 4; ++m)
                #pragma unroll
                for (int n = 0; n < 5; ++n) {
                    int gc = col0 + wc * 80 + n * 16 + col16;
                    float bia = bqkv[gc];
                    #pragma unroll
                    for (int r = 0; r < 4; ++r) {
                        int gr = row0 + wr * 64 + m * 16 + quad * 4 + r;
                        if (gr >= N_NODES) continue;
                        float v = acc[m][n][r] + bia;
                        if (gc < DIM_QK) {
                            qk[(size_t)gr * DIM_QK + gc] = v;
                        } else {
#if V_FP8
                            int pk = __builtin_amdgcn_cvt_pk_fp8_f32(v * VSCALE, 0.f, 0, false);
                            ((unsigned char*)v_tab)[(size_t)gr * DIM_H + (gc - DIM_QK)] =
                                (unsigned char)(pk & 0xff);
#else
                            v_tab[(size_t)gr * DIM_H + (gc - DIM_QK)] = f2bf(v);
#endif
                        }
                    }
                }
        }
    }
    gbar(bar, 2);

    // ---------------- P4: fused per-row attention (dedup + softmax + v-gather) --------
    // Waves fully independent (wave-private LDS slices + in-wave fences, no barriers).
    {
        int*   dstW = (int*)SMEM + wave * MAXD;                     // [MAXD]
        float* wW   = (float*)(SMEM + 3072) + wave * MAXD;          // [MAXD]
        float* qW   = (float*)(SMEM + 6144) + wave * DIM_C;         // [32]
        for (int row = bid * 4 + wave; row < N_NODES; row += NBLK * 4) {
            __threadfence_block();               // prior-iter LDS reads done before overwrite
            int d = deg[row];
            if (d > MAXD) d = MAXD;
            const int* crow = col + (size_t)row * MAXD;

            for (int p = lane; p < d; p += 64) dstW[p] = crow[p];
            if (lane < DIM_C) qW[lane] = qk[(size_t)row * DIM_QK + lane];
            __threadfence_block();

            float mysum = 0.f;
            if (d <= 64) {
                int mydst = (lane < d) ? dstW[lane] : -1;
                bool dup = false;
                for (int k2 = 0; k2 < d - 1; ++k2) {    // dynamic bound: ~31 iters avg, not 63
                    int other = __shfl(mydst, k2, 64);
                    dup = dup || (k2 < lane && other == mydst);
                }
                float w = 0.f;
                if (lane < d && !dup) {
                    const float4* kp = (const float4*)(qk + (size_t)mydst * DIM_QK + DIM_C);
                    float s = 0.f;
                    #pragma unroll
                    for (int i = 0; i < DIM_C / 4; ++i) {
                        float4 b = kp[i];
                        s += qW[4 * i + 0] * b.x + qW[4 * i + 1] * b.y
                           + qW[4 * i + 2] * b.z + qW[4 * i + 3] * b.w;
                    }
                    w = expf(s * SCALE);
                }
                wW[lane] = w;
                mysum = w;
            } else {
                for (int p = lane; p < d; p += 64) {
                    int mydst = dstW[p];
                    bool dup = false;
                    for (int j = 0; j < p; ++j) dup = dup || (dstW[j] == mydst);
                    float w = 0.f;
                    if (!dup) {
                        const float4* kp = (const float4*)(qk + (size_t)mydst * DIM_QK + DIM_C);
                        float s = 0.f;
                        #pragma unroll
                        for (int i = 0; i < DIM_C / 4; ++i) {
                            float4 b = kp[i];
                            s += qW[4 * i + 0] * b.x + qW[4 * i + 1] * b.y
                               + qW[4 * i + 2] * b.z + qW[4 * i + 3] * b.w;
                        }
                        w = expf(s * SCALE);
                    }
                    wW[p] = w;
                    mysum += w;
                }
            }
            #pragma unroll
            for (int off = 32; off; off >>= 1) mysum += __shfl_down(mysum, off, 64);
            float total = __shfl(mysum, 0, 64);
#if V_FP8
            float inv = (d > 0 && total > 0.f) ? 1.0f / (total * VSCALE) : 0.f;
#else
            float inv = (d > 0 && total > 0.f) ? 1.0f / total : 0.f;
#endif
            __threadfence_block();

            float4 acc = make_float4(0.f, 0.f, 0.f, 0.f);
#if V_FP8
            const uint32_t* vb = (const uint32_t*)v_tab;   // fp8 row = 64 dwords
#else
            const uint2* vb = (const uint2*)v_tab;         // bf16 row = 64 uint2
#endif
            for (int p0 = 0; p0 < d; p0 += 16) {
                int j[16]; float w[16];
                #pragma unroll
                for (int t = 0; t < 16; ++t) {
                    int idx = p0 + t;
                    bool in = idx < d;
                    j[t] = in ? dstW[idx] : 0;
                    w[t] = in ? wW[idx] : 0.f;
                }
#if V_FP8
                uint32_t r[16];
                #pragma unroll
                for (int t = 0; t < 16; ++t) r[t] = vb[(size_t)j[t] * 64 + lane];
                #pragma unroll
                for (int t = 0; t < 16; ++t) {
                    floatx2 lo = __builtin_amdgcn_cvt_pk_f32_fp8(r[t], false);
                    floatx2 hi = __builtin_amdgcn_cvt_pk_f32_fp8(r[t], true);
                    acc.x += w[t] * lo.x; acc.y += w[t] * lo.y;
                    acc.z += w[t] * hi.x; acc.w += w[t] * hi.y;
                }
#else
                uint2 r[16];
                #pragma unroll
                for (int t = 0; t < 16; ++t) r[t] = vb[(size_t)j[t] * 64 + lane];
                #pragma unroll
                for (int t = 0; t < 16; ++t) {
                    acc.x += w[t] * bf2f_lo(r[t].x);
                    acc.y += w[t] * bf2f_hi(r[t].x);
                    acc.z += w[t] * bf2f_lo(r[t].y);
                    acc.w += w[t] * bf2f_hi(r[t].y);
                }
#endif
            }
            acc.x *= inv; acc.y *= inv; acc.z *= inv; acc.w *= inv;
            uint2 o;
            o.x = (uint32_t)f2bf(acc.x) | ((uint32_t)f2bf(acc.y) << 16);
            o.y = (uint32_t)f2bf(acc.z) | ((uint32_t)f2bf(acc.w) << 16);
            *(uint2*)(cat_bf + (size_t)row * DIM_CAT + DIM_H + lane * 4) = o;
        }
    }
    gbar(bar, 3);

    // ---------------- P5: out = relu(cat@W1+b1)@W2 + b2 ----------------
    // BM=64. Phase A: 4 waves each 64x64 (acc 4x4, 8 ds_reads / 16 MFMA), z -> LDS.
    // Phase B: z @ W2T^T (W2T 32 KB, L2-hot). 157 jobs.
    {
        constexpr int TP = 260;
        short* As   = (short*)SMEM;              // 64 x PAD  (5,120 B)
        short* BsTs = (short*)(SMEM + 5120);     // Bs 256xPAD (20,480) aliases Ts 64xTP (33,280)
        short* Bs = BsTs;
        short* Ts = BsTs;
        if (bid < (N_NODES + 63) / 64) {   // 157
            const int row0 = bid * 64;
            floatx4 acc[4][4] = {};
            for (int k0 = 0; k0 < DIM_CAT; k0 += 32) {
                {
                    int gr = row0 + sr;
                    short8 v = {};
                    if (gr < N_NODES) v = *(const short8*)(cat_bf + (size_t)gr * DIM_CAT + k0 + sc);
                    *(short8*)(As + sr * PAD + sc) = v;
                }
                #pragma unroll
                for (int p = 0; p < 4; ++p) {
                    int r = sr + p * 64;
                    *(short8*)(Bs + r * PAD + sc) =
                        *(const short8*)(W1T + (size_t)r * DIM_CAT + k0 + sc);
                }
                __syncthreads();
                short8 af[4], bf[4];
                #pragma unroll
                for (int m = 0; m < 4; ++m)
                    af[m] = *(const short8*)(As + (m * 16 + col16) * PAD + quad * 8);
                #pragma unroll
                for (int n = 0; n < 4; ++n)
                    bf[n] = *(const short8*)(Bs + (wave * 64 + n * 16 + col16) * PAD + quad * 8);
                #pragma unroll
                for (int m = 0; m < 4; ++m)
                    #pragma unroll
                    for (int n = 0; n < 4; ++n)
                        acc[m][n] = MFMA16(af[m], bf[n], acc[m][n], 0, 0, 0);
                __syncthreads();   // Bs reads done before next staging / Ts overwrite
            }
            // epilogue A: bias + relu -> bf16 z tile in Ts
            #pragma unroll
            for (int m = 0; m < 4; ++m)
                #pragma unroll
                for (int n = 0; n < 4; ++n) {
                    int gc = wave * 64 + n * 16 + col16;
                    float bia = b1[gc];
                    #pragma unroll
                    for (int r = 0; r < 4; ++r) {
                        int lr = m * 16 + quad * 4 + r;
                        Ts[lr * TP + gc] = (short)f2bf(fmaxf(acc[m][n][r] + bia, 0.f));
                    }
                }
            __syncthreads();
            // phase B: out = z @ W2T^T + b2, K=256, N=64
            floatx4 acc2[4] = {};
            for (int k0 = 0; k0 < DIM_H; k0 += 32) {
                short8 a = *(const short8*)(Ts + (wave * 16 + col16) * TP + k0 + quad * 8);
                #pragma unroll
                for (int n = 0; n < 4; ++n) {
                    short8 b = *(const short8*)(W2T + (size_t)(n * 16 + col16) * DIM_H + k0 + quad * 8);
                    acc2[n] = MFMA16(a, b, acc2[n], 0, 0, 0);
                }
            }
            #pragma unroll
            for (int n = 0; n < 4; ++n) {
                int gc = n * 16 + col16;
                float bia = b2[gc];
                #pragma unroll
                for (int r = 0; r < 4; ++r) {
                    int gr = row0 + wave * 16 + quad * 4 + r;
                    if (gr < N_NODES) out[(size_t)gr * DIM_OUT + gc] = acc2[n][r] + bia;
                }
            }
        }
    }
}

// ---------------- launcher ----------------
extern "C" void kernel_launch(void* const* d_in, const int* in_sizes, int n_in,
                              void* d_out, int out_size, void* d_ws, size_t ws_size,
                              hipStream_t stream) {
    (void)in_sizes; (void)n_in; (void)out_size; (void)ws_size;
    const float* x    = (const float*)d_in[0];
    const int*   ei   = (const int*)d_in[1];
    const float* W_in = (const float*)d_in[2];
    const float* b_in = (const float*)d_in[3];
    const float* Wq   = (const float*)d_in[4];
    const float* bq   = (const float*)d_in[5];
    const float* Wk   = (const float*)d_in[6];
    const float* bk   = (const float*)d_in[7];
    const float* Wv   = (const float*)d_in[8];
    const float* bv   = (const float*)d_in[9];
    const float* W1   = (const float*)d_in[10];
    const float* b1   = (const float*)d_in[11];
    const float* W2   = (const float*)d_in[12];
    const float* b2   = (const float*)d_in[13];
    float* out = (float*)d_out;

    uint32_t* ws      = (uint32_t*)d_ws;
    int*      deg     = (int*)(ws + OFF_DEG);
    int*      bar     = (int*)(ws + OFF_BAR);
    int*      col     = (int*)(ws + OFF_COL);
    float*    qk      = (float*)(ws + OFF_QK);
    float*    bqkv    = (float*)(ws + OFF_BQKV);
    unsigned short* v_tab  = (unsigned short*)(ws + OFF_VT);
    unsigned short* x_bf   = (unsigned short*)(ws + OFF_XBF);
    unsigned short* cat_bf = (unsigned short*)(ws + OFF_CATBF);
    unsigned short* WinT   = (unsigned short*)(ws + OFF_WINT);
    unsigned short* WqkvT  = (unsigned short*)(ws + OFF_WQKVT);
    unsigned short* W1T    = (unsigned short*)(ws + OFF_W1T);
    unsigned short* W2T    = (unsigned short*)(ws + OFF_W2T);

    // zero deg + grid-barrier counters (40,064 B), then the persistent megakernel
    hipMemsetAsync(ws, 0, (OFF_BAR + 16) * sizeof(uint32_t), stream);
    hipLaunchKernelGGL(mega, dim3(NBLK), dim3(NTHR), 0, stream,
                       x, ei, W_in, b_in, Wq, bq, Wk, bk, Wv, bv, W1, b1, W2, b2, out,
                       deg, bar, col, qk, bqkv, v_tab, x_bf, cat_bf,
                       WinT, WqkvT, W1T, W2T);
}